// Round 2
// baseline (862.839 us; speedup 1.0000x reference)
//
#include <hip/hip_runtime.h>
#include <stdint.h>

#define NROW 8192          // N
#define DDIM 512           // D
#define BB   8             // B
#define PP   4             // P
#define MTOT (BB*NROW)     // 65536 rows

typedef __attribute__((ext_vector_type(8))) short short8;            // 8 bf16 (4 VGPRs)
typedef __attribute__((ext_vector_type(4))) float floatx4;
typedef __attribute__((ext_vector_type(4))) unsigned int uintx4;

// ---- bf16 helpers ----
__device__ inline float bf2f(unsigned short h) { return __uint_as_float(((unsigned)h) << 16); }
__device__ inline unsigned short f2bf_rn(float f) {
    return (unsigned short)((__float_as_uint(f) + 0x8000u) >> 16);   // round-half-up
}
// pack two fp32 -> two bf16 in one u32 (elem0 = a, elem1 = b): 2 adds + 1 v_perm
__device__ inline unsigned pack_bf16(float a, float b) {
    unsigned ua = __float_as_uint(a) + 0x8000u;
    unsigned ub = __float_as_uint(b) + 0x8000u;
    return __builtin_amdgcn_perm(ub, ua, 0x07060302u);
}

template <typename T> __device__ inline float loadF(const T* p);
template <> __device__ inline float loadF<float>(const float* p) { return *p; }
template <> __device__ inline float loadF<unsigned short>(const unsigned short* p) { return bf2f(*p); }
template <typename T> __device__ inline void storeF(T* p, float f);
template <> __device__ inline void storeF<float>(float* p, float f) { *p = f; }
template <> __device__ inline void storeF<unsigned short>(unsigned short* p, float f) { *p = f2bf_rn(f); }

// ---- histogram: cnt[i][r] = multiplicity of r in groups[i] ----
__global__ void hist_kernel(const int* __restrict__ groups, float* __restrict__ cnt) {
    int t = blockIdx.x * 256 + threadIdx.x;     // 0..32767
    int i = t >> 13;
    atomicAdd(&cnt[i * NROW + groups[t]], 1.0f);
}

// ---- W -> bf16, pre-swizzled into MFMA B-fragment order ----
// Wsw[i][kb 0..15][gtile 0..31][lane 0..63][e 0..7] = bf16(W[i][k][n])
//   n = gtile*16 + (lane&15), k = kb*32 + (lane>>4)*8 + e
__global__ void transpose_w(const float* __restrict__ W, unsigned short* __restrict__ Wsw) {
    int u = blockIdx.x * 256 + threadIdx.x;     // 0..131071 (one 16B chunk each)
    int i    = u >> 15;
    int kb   = (u >> 11) & 15;
    int gt   = (u >> 6) & 31;
    int lane = u & 63;
    int n  = gt * 16 + (lane & 15);
    int k0 = kb * 32 + (lane >> 4) * 8;
    const float* wp = W + i * 262144 + k0 * 512 + n;
    unsigned hp[4];
    #pragma unroll
    for (int j = 0; j < 4; ++j)
        hp[j] = pack_bf16(wp[(2*j) * 512], wp[(2*j+1) * 512]);
    uintx4 w = {hp[0], hp[1], hp[2], hp[3]};
    *(uintx4*)(Wsw + (size_t)u * 8) = w;
}

// ---- fused round GEMM, wave-per-i ----
// Block computes a 64x64 output tile. Wave w accumulates the UNSCALED
// product  src_tile @ W_w  over K=512 (i == wave). Per-row count scaling
// c_w[m] is applied ONCE to the f32 accumulator at the epilogue, then the
// 4 waves' contributions are combined through LDS:
//   dst = src + scale * sum_w c_w[m] * (src @ W_w)[m,n]
// A: staged unscaled bf16 in LDS once per kb (shared by all 4 waves),
//    fragment-contiguous layout -> conflict-free ds_read_b128.
// B: fragments loaded directly from Wsw (2 MB, L2-resident), no LDS.
// One __syncthreads per kb (vs 8 in the previous structure).
template <typename SrcT, typename DstT>
__global__ __launch_bounds__(256, 2)
void gemm_round(const SrcT* __restrict__ src, const unsigned short* __restrict__ Wsw,
                const float* __restrict__ cnt, DstT* __restrict__ dst, float scale)
{
    __shared__ __align__(16) unsigned short sA[2][2048];   // dbuf: 4 mtiles * 64 lanes * 8
    __shared__ __align__(16) float sE[PP][16][64];         // epilogue combine buffer

    const int t    = threadIdx.x;
    const int wave = t >> 6;                 // wave == i
    const int lane = t & 63;
    const int m0   = blockIdx.x * 64;
    const int nb   = blockIdx.y;             // n0 = nb*64

    // per-lane count scales for this wave's i, in C-fragment row layout:
    // acc[a][b][q] has row m0 + a*16 + (lane>>4)*4 + q
    float cs[4][4];
    #pragma unroll
    for (int a = 0; a < 4; ++a)
        #pragma unroll
        for (int q = 0; q < 4; ++q)
            cs[a][q] = cnt[wave * NROW + ((m0 + a*16 + (lane >> 4)*4 + q) & (NROW - 1))];

    // A staging: thread t owns 8 consecutive k-elems of one row each kb.
    //   row  = (t>>6)*16 + (t&15)       (matches lane slot (a*64+lane))
    //   cols = kb*32 + ((t>>4)&3)*8 .. +8
    const int srow = ((t >> 6) << 4) | (t & 15);
    const int scol = ((t >> 4) & 3) * 8;
    const SrcT* sp = src + (size_t)(m0 + srow) * DDIM + scol;
    unsigned short* sAw0 = &sA[0][t * 8];
    unsigned short* sAw1 = &sA[1][t * 8];

    // B fragment base: Wsw[((wave*16+kb)*32 + nb*4 + b)*512 + lane*8]
    const unsigned short* bp = Wsw + ((size_t)(wave * 16) * 32 + nb * 4) * 512 + lane * 8;

    floatx4 acc[4][4] = {};
    short8 Bc[2][4];

    // ---- prologue: B(kb=0) to regs, A(kb=0) to sA[0]
    #pragma unroll
    for (int b = 0; b < 4; ++b)
        Bc[0][b] = *(const short8*)(bp + b * 512);
    if constexpr (sizeof(SrcT) == 4) {
        floatx4 v0 = *(const floatx4*)(sp);
        floatx4 v1 = *(const floatx4*)(sp + 4);
        uintx4 w = { pack_bf16(v0[0], v0[1]), pack_bf16(v0[2], v0[3]),
                     pack_bf16(v1[0], v1[1]), pack_bf16(v1[2], v1[3]) };
        *(uintx4*)sAw0 = w;
    } else {
        *(uintx4*)sAw0 = *(const uintx4*)sp;
    }
    __syncthreads();

    #pragma unroll
    for (int kb = 0; kb < 16; ++kb) {
        const int cur = kb & 1;
        unsigned short* sAwn = cur ? sAw0 : sAw1;

        // prefetch next kb: A source -> regs, B frags -> regs (stay in flight
        // across the MFMA block; consumed/drained by iter end)
        floatx4 v0, v1; uintx4 vr;
        if (kb < 15) {
            if constexpr (sizeof(SrcT) == 4) {
                v0 = *(const floatx4*)(sp + (kb + 1) * 32);
                v1 = *(const floatx4*)(sp + (kb + 1) * 32 + 4);
            } else {
                vr = *(const uintx4*)(sp + (kb + 1) * 32);
            }
            #pragma unroll
            for (int b = 0; b < 4; ++b)
                Bc[cur ^ 1][b] = *(const short8*)(bp + (size_t)(kb + 1) * 16384 + b * 512);
        }

        // A fragments from LDS (conflict-free: base + lane*16B)
        short8 af[4];
        #pragma unroll
        for (int a = 0; a < 4; ++a)
            af[a] = *(const short8*)&sA[cur][(a * 64 + lane) * 8];

        #pragma unroll
        for (int a = 0; a < 4; ++a)
            #pragma unroll
            for (int b = 0; b < 4; ++b)
                acc[a][b] = __builtin_amdgcn_mfma_f32_16x16x32_bf16(af[a], Bc[cur][b], acc[a][b], 0, 0, 0);

        // stage next kb's A tile (unscaled) into the other buffer
        if (kb < 15) {
            if constexpr (sizeof(SrcT) == 4) {
                uintx4 w = { pack_bf16(v0[0], v0[1]), pack_bf16(v0[2], v0[3]),
                             pack_bf16(v1[0], v1[1]), pack_bf16(v1[2], v1[3]) };
                *(uintx4*)sAwn = w;
            } else {
                *(uintx4*)sAwn = vr;
            }
        }
        __syncthreads();
    }

    // ---- epilogue: scale own acc by c_i[row], combine 4 waves through LDS
    // chunk a: 16 rows x 64 cols
    #pragma unroll
    for (int a = 0; a < 4; ++a) {
        #pragma unroll
        for (int b = 0; b < 4; ++b)
            #pragma unroll
            for (int q = 0; q < 4; ++q)
                sE[wave][(lane >> 4) * 4 + q][b * 16 + (lane & 15)] = acc[a][b][q] * cs[a][q];
        __syncthreads();
        #pragma unroll
        for (int e = 0; e < 4; ++e) {
            const int r = wave * 4 + e;
            const size_t m = (size_t)(m0 + a * 16 + r);
            const size_t n = (size_t)nb * 64 + lane;
            const float sum = sE[0][r][lane] + sE[1][r][lane] + sE[2][r][lane] + sE[3][r][lane];
            storeF(dst + m * DDIM + n, loadF(src + m * DDIM + n) + scale * sum);
        }
        if (a < 3) __syncthreads();
    }
}

extern "C" void kernel_launch(void* const* d_in, const int* in_sizes, int n_in,
                              void* d_out, int out_size, void* d_ws, size_t ws_size,
                              hipStream_t stream) {
    const float* x      = (const float*)d_in[0];   // (8, 8192, 512) fp32
    const float* W      = (const float*)d_in[1];   // (4, 512, 512) fp32
    const int*   groups = (const int*)d_in[2];     // (4, 512, 16) int32
    float* out = (float*)d_out;                    // (8, 8192, 512) fp32

    char* ws = (char*)d_ws;
    float*          cnt = (float*)ws;                               // 128 KB
    unsigned short* Wsw = (unsigned short*)(ws + 131072);           // 2 MB
    unsigned short* U   = (unsigned short*)(ws + 131072 + 2097152); // 64 MB bf16

    hipMemsetAsync(cnt, 0, PP * NROW * sizeof(float), stream);
    hist_kernel<<<32768 / 256, 256, 0, stream>>>(groups, cnt);
    transpose_w<<<131072 / 256, 256, 0, stream>>>(W, Wsw);

    dim3 grid(MTOT / 64, DDIM / 64);               // (1024, 8)
    // round 1: x (fp32) -> out (fp32)
    gemm_round<float, float><<<grid, 256, 0, stream>>>(x, Wsw, cnt, out, 1.0f);
    // round 2: out (fp32) -> U (bf16)
    gemm_round<float, unsigned short><<<grid, 256, 0, stream>>>(out, Wsw, cnt, U, 0.5f);
    // round 3: U (bf16) -> out (fp32)
    gemm_round<unsigned short, float><<<grid, 256, 0, stream>>>(U, Wsw, cnt, out, 1.0f / 3.0f);
}

// Round 3
// 776.149 us; speedup vs baseline: 1.1117x; 1.1117x over previous
//
#include <hip/hip_runtime.h>
#include <stdint.h>

#define NROW 8192          // N
#define DDIM 512           // D
#define BB   8             // B
#define PP   4             // P
#define MTOT (BB*NROW)     // 65536 rows

typedef __attribute__((ext_vector_type(8))) short short8;            // 8 bf16 (4 VGPRs)
typedef __attribute__((ext_vector_type(4))) float floatx4;
typedef __attribute__((ext_vector_type(4))) unsigned int uintx4;

// ---- bf16 helpers ----
__device__ inline float bf2f(unsigned short h) { return __uint_as_float(((unsigned)h) << 16); }
__device__ inline unsigned short f2bf_rn(float f) {
    return (unsigned short)((__float_as_uint(f) + 0x8000u) >> 16);   // round-half-up
}
// pack two fp32 -> two bf16 in one u32 (elem0 = a, elem1 = b): 2 adds + 1 v_perm
__device__ inline unsigned pack_bf16(float a, float b) {
    unsigned ua = __float_as_uint(a) + 0x8000u;
    unsigned ub = __float_as_uint(b) + 0x8000u;
    return __builtin_amdgcn_perm(ub, ua, 0x07060302u);
}
__device__ inline uintx4 packA(const floatx4& v0, const floatx4& v1) {
    uintx4 w = { pack_bf16(v0[0], v0[1]), pack_bf16(v0[2], v0[3]),
                 pack_bf16(v1[0], v1[1]), pack_bf16(v1[2], v1[3]) };
    return w;
}

template <typename T> __device__ inline float loadF(const T* p);
template <> __device__ inline float loadF<float>(const float* p) { return *p; }
template <> __device__ inline float loadF<unsigned short>(const unsigned short* p) { return bf2f(*p); }
template <typename T> __device__ inline void storeF(T* p, float f);
template <> __device__ inline void storeF<float>(float* p, float f) { *p = f; }
template <> __device__ inline void storeF<unsigned short>(unsigned short* p, float f) { *p = f2bf_rn(f); }

// LDS-only barrier: orders ds_write->ds_read across waves WITHOUT draining
// vmcnt, so global prefetch loads (B frags, next A tile) stay in flight.
__device__ inline void block_sync_lds() {
    __builtin_amdgcn_sched_barrier(0);
    asm volatile("s_waitcnt lgkmcnt(0)" ::: "memory");
    __builtin_amdgcn_s_barrier();
    __builtin_amdgcn_sched_barrier(0);
}

// ---- histogram: cnt[i][r] = multiplicity of r in groups[i] ----
__global__ void hist_kernel(const int* __restrict__ groups, float* __restrict__ cnt) {
    int t = blockIdx.x * 256 + threadIdx.x;     // 0..32767
    int i = t >> 13;
    atomicAdd(&cnt[i * NROW + groups[t]], 1.0f);
}

// ---- W -> bf16, pre-swizzled into MFMA B-fragment order ----
// Wsw[i][kb 0..15][gtile 0..31][lane 0..63][e 0..7] = bf16(W[i][k][n])
//   n = gtile*16 + (lane&15), k = kb*32 + (lane>>4)*8 + e
__global__ void transpose_w(const float* __restrict__ W, unsigned short* __restrict__ Wsw) {
    int u = blockIdx.x * 256 + threadIdx.x;     // 0..131071 (one 16B chunk each)
    int i    = u >> 15;
    int kb   = (u >> 11) & 15;
    int gt   = (u >> 6) & 31;
    int lane = u & 63;
    int n  = gt * 16 + (lane & 15);
    int k0 = kb * 32 + (lane >> 4) * 8;
    const float* wp = W + i * 262144 + k0 * 512 + n;
    unsigned hp[4];
    #pragma unroll
    for (int j = 0; j < 4; ++j)
        hp[j] = pack_bf16(wp[(2*j) * 512], wp[(2*j+1) * 512]);
    uintx4 w = {hp[0], hp[1], hp[2], hp[3]};
    *(uintx4*)(Wsw + (size_t)u * 8) = w;
}

// ---- fused round GEMM, wave-per-i, BK=64 per barrier ----
// Block computes a 64x64 output tile; wave w accumulates UNSCALED src@W_w
// over K=512. Scaling by c_w[row] applied once to the f32 accumulator in
// the epilogue; 4 waves combined through LDS:
//   dst = src + scale * sum_w c_w[m] * (src @ W_w)[m,n]
// Main loop: 8 iterations x (2 kb sub-phases of 16 MFMA each).
// A: unscaled bf16 LDS tile (dbuf), staged once per iter, fragment layout.
// B: fragments register-direct from L2-resident Wsw, pipelined 1 sub ahead.
// Barrier = lgkmcnt(0)+s_barrier only -> global loads live across it.
template <typename SrcT, typename DstT>
__global__ __launch_bounds__(256, 2)
void gemm_round(const SrcT* __restrict__ src, const unsigned short* __restrict__ Wsw,
                const float* __restrict__ cnt, DstT* __restrict__ dst, float scale)
{
    __shared__ __align__(16) unsigned char smem[16768];
    unsigned short* sA = (unsigned short*)smem;      // [buf 2][sub 2][2048]
    float*          sE = (float*)smem;               // [PP][16][65] epilogue

    const int t    = threadIdx.x;
    const int wave = t >> 6;                 // wave == i
    const int lane = t & 63;
    const int nb   = blockIdx.x;             // 0..7, fastest-varying
    const int m0   = blockIdx.y * 64;

    // A staging: thread t owns 8 consecutive k-elems of one row per sub.
    const int srow = ((t >> 6) << 4) | (t & 15);
    const int scol = ((t >> 4) & 3) * 8;
    const SrcT* sp = src + (size_t)(m0 + srow) * DDIM + scol;
    unsigned short* sAw = sA + t * 8;        // + (buf*2+sub)*2048

    // B fragment base: Wsw[((wave*16+kb)*32 + nb*4 + b)*512 + lane*8]
    const unsigned short* bp = Wsw + ((size_t)(wave * 16) * 32 + nb * 4) * 512 + lane * 8;

    floatx4 acc[4][4] = {};
    short8 Bf[2][4];          // sub-phase ring
    floatx4 pf[2][2];         // A src prefetch (fp32 path) [sub][half]
    uintx4  pb[2];            // A src prefetch (bf16 path) [sub]

    // ---- prologue: stage it=0 A, prefetch it=1 A, load B(kb=0) ----
    #pragma unroll
    for (int s = 0; s < 2; ++s) {
        if constexpr (sizeof(SrcT) == 4) {
            floatx4 v0 = *(const floatx4*)(sp + s * 32);
            floatx4 v1 = *(const floatx4*)(sp + s * 32 + 4);
            *(uintx4*)(sAw + s * 2048) = packA(v0, v1);
        } else {
            *(uintx4*)(sAw + s * 2048) = *(const uintx4*)(sp + s * 32);
        }
    }
    #pragma unroll
    for (int s = 0; s < 2; ++s) {
        if constexpr (sizeof(SrcT) == 4) {
            pf[s][0] = *(const floatx4*)(sp + (2 + s) * 32);
            pf[s][1] = *(const floatx4*)(sp + (2 + s) * 32 + 4);
        } else {
            pb[s] = *(const uintx4*)(sp + (2 + s) * 32);
        }
    }
    #pragma unroll
    for (int b = 0; b < 4; ++b)
        Bf[0][b] = *(const short8*)(bp + b * 512);
    block_sync_lds();

    #pragma unroll
    for (int it = 0; it < 8; ++it) {
        const int buf = it & 1;
        const unsigned short* sAr = sA + buf * 4096;

        // B for sub1 of this iteration (in flight during sub0 MFMAs)
        #pragma unroll
        for (int b = 0; b < 4; ++b)
            Bf[1][b] = *(const short8*)(bp + (size_t)(2 * it + 1) * 16384 + b * 512);

        // ---- sub0: 16 MFMA
        {
            short8 af[4];
            #pragma unroll
            for (int a = 0; a < 4; ++a)
                af[a] = *(const short8*)(sAr + (a * 64 + lane) * 8);
            #pragma unroll
            for (int a = 0; a < 4; ++a)
                #pragma unroll
                for (int b = 0; b < 4; ++b)
                    acc[a][b] = __builtin_amdgcn_mfma_f32_16x16x32_bf16(af[a], Bf[0][b], acc[a][b], 0, 0, 0);
        }

        // B for sub0 of next iteration
        if (it < 7) {
            #pragma unroll
            for (int b = 0; b < 4; ++b)
                Bf[0][b] = *(const short8*)(bp + (size_t)(2 * it + 2) * 16384 + b * 512);
        }

        // ---- sub1: 16 MFMA
        {
            short8 af[4];
            #pragma unroll
            for (int a = 0; a < 4; ++a)
                af[a] = *(const short8*)(sAr + 2048 + (a * 64 + lane) * 8);
            #pragma unroll
            for (int a = 0; a < 4; ++a)
                #pragma unroll
                for (int b = 0; b < 4; ++b)
                    acc[a][b] = __builtin_amdgcn_mfma_f32_16x16x32_bf16(af[a], Bf[1][b], acc[a][b], 0, 0, 0);
        }

        // stage next-iter A (regs loaded one iteration ago), prefetch it+2
        if (it < 7) {
            unsigned short* sAn = sA + (buf ^ 1) * 4096 + t * 8;
            #pragma unroll
            for (int s = 0; s < 2; ++s) {
                if constexpr (sizeof(SrcT) == 4)
                    *(uintx4*)(sAn + s * 2048) = packA(pf[s][0], pf[s][1]);
                else
                    *(uintx4*)(sAn + s * 2048) = pb[s];
            }
            if (it < 6) {
                #pragma unroll
                for (int s = 0; s < 2; ++s) {
                    const int c = (2 * (it + 2) + s) * 32;
                    if constexpr (sizeof(SrcT) == 4) {
                        pf[s][0] = *(const floatx4*)(sp + c);
                        pf[s][1] = *(const floatx4*)(sp + c + 4);
                    } else {
                        pb[s] = *(const uintx4*)(sp + c);
                    }
                }
            }
        }
        block_sync_lds();
    }

    // ---- epilogue: scale own acc by c_i[row], combine 4 waves through LDS
    // (sE overlays sA; safe after final barrier). Row stride 65 = pad.
    float cs[4][4];
    #pragma unroll
    for (int a = 0; a < 4; ++a)
        #pragma unroll
        for (int q = 0; q < 4; ++q)
            cs[a][q] = cnt[wave * NROW + ((m0 + a * 16 + (lane >> 4) * 4 + q) & (NROW - 1))];

    #pragma unroll
    for (int a = 0; a < 4; ++a) {
        float* se = sE + wave * 1040;        // 16*65 floats per wave region
        #pragma unroll
        for (int b = 0; b < 4; ++b)
            #pragma unroll
            for (int q = 0; q < 4; ++q)
                se[((lane >> 4) * 4 + q) * 65 + b * 16 + (lane & 15)] = acc[a][b][q] * cs[a][q];
        __syncthreads();
        #pragma unroll
        for (int e = 0; e < 4; ++e) {
            const int r = wave * 4 + e;
            const size_t m = (size_t)(m0 + a * 16 + r);
            const size_t n = (size_t)nb * 64 + lane;
            const float sum = sE[0 * 1040 + r * 65 + lane] + sE[1 * 1040 + r * 65 + lane]
                            + sE[2 * 1040 + r * 65 + lane] + sE[3 * 1040 + r * 65 + lane];
            storeF(dst + m * DDIM + n, loadF(src + m * DDIM + n) + scale * sum);
        }
        if (a < 3) __syncthreads();
    }
}

extern "C" void kernel_launch(void* const* d_in, const int* in_sizes, int n_in,
                              void* d_out, int out_size, void* d_ws, size_t ws_size,
                              hipStream_t stream) {
    const float* x      = (const float*)d_in[0];   // (8, 8192, 512) fp32
    const float* W      = (const float*)d_in[1];   // (4, 512, 512) fp32
    const int*   groups = (const int*)d_in[2];     // (4, 512, 16) int32
    float* out = (float*)d_out;                    // (8, 8192, 512) fp32

    char* ws = (char*)d_ws;
    float*          cnt = (float*)ws;                               // 128 KB
    unsigned short* Wsw = (unsigned short*)(ws + 131072);           // 2 MB
    unsigned short* U   = (unsigned short*)(ws + 131072 + 2097152); // 64 MB bf16

    hipMemsetAsync(cnt, 0, PP * NROW * sizeof(float), stream);
    hist_kernel<<<32768 / 256, 256, 0, stream>>>(groups, cnt);
    transpose_w<<<131072 / 256, 256, 0, stream>>>(W, Wsw);

    // nb fastest-varying: the 8 blocks sharing an A-tile dispatch together
    // (A via L3 after first fetch; each nb's 256KB B-slice pins to one XCD L2)
    dim3 grid(DDIM / 64, MTOT / 64);               // (8, 1024)
    // round 1: x (fp32) -> out (fp32)
    gemm_round<float, float><<<grid, 256, 0, stream>>>(x, Wsw, cnt, out, 1.0f);
    // round 2: out (fp32) -> U (bf16)
    gemm_round<float, unsigned short><<<grid, 256, 0, stream>>>(out, Wsw, cnt, U, 0.5f);
    // round 3: U (bf16) -> out (fp32)
    gemm_round<unsigned short, float><<<grid, 256, 0, stream>>>(U, Wsw, cnt, out, 1.0f / 3.0f);
}